// Round 14
// baseline (404.309 us; speedup 1.0000x reference)
//
#include <hip/hip_runtime.h>
#include <math.h>

#define NNODES 100000
#define NEDGES 1600000
#define NPOS   4096      // 32 seqs * 128 steps
#define NSEQ   32
#define TSTEPS 128

typedef float f32x4 __attribute__((ext_vector_type(4)));
typedef unsigned u32x4 __attribute__((ext_vector_type(4)));
typedef _Float16 h2v __attribute__((ext_vector_type(2)));

// ---- ws layout (bytes) ----
#define OFF_SLOT   0          // int[100000]  (dead after k_pregemm)
#define OFF_AGG    400128     // float[4096*128] (dead after k_pregemm; overlaid by wh16)
#define OFF_CNT    2497280    // float[4096]
#define OFF_WF     2513664    // float[1024*128]
#define OFF_BIASF  3037952    // float[1024]
#define OFF_PREG   3042048    // float[128][32s][8m][4q][32d]
#define OFF_HS     19819264   // float[129][32][256]
// fp16 weight images overlay the dead agg region (valid only after k_pregemm).
// Measured model (R10-R13): the DS pipe (~12 cyc per ds_read_b128 wave-inst,
// shared per-CU) was the binding constraint at 272 insts/step -- HALF of them
// wave-uniform h-broadcasts delivering 16 unique bytes at full cost. VMEM
// overlaps at ~96% of ~100 B/cyc with 16 waves. VGPR budget @1024thr = 64.
//   wR: u32[24][1024]    6 quads/thread register-resident    98304 B
//   wL: u32x4[9][1024]   9 quads/thread LDS-resident        147456 B
//   wS: u32x4[17][1024]  17 quads/thread L2-streamed/step   278528 B
#define OFF_WR  OFF_AGG
#define OFF_WL  (OFF_AGG + 98304)
#define OFF_WS  (OFF_AGG + 245760)

// fp16 dot2 with f32 accumulate: D = w.h[0]*h.h[0] + w.h[1]*h.h[1] + acc.
static __device__ __forceinline__ float fdot2(unsigned w, unsigned h, float acc) {
#if __has_builtin(__builtin_amdgcn_fdot2)
  h2v wv, hv;
  __builtin_memcpy(&wv, &w, 4);
  __builtin_memcpy(&hv, &h, 4);
  return __builtin_amdgcn_fdot2(wv, hv, acc, false);
#else
  asm("v_dot2_f32_f16 %0, %1, %2, %0" : "+v"(acc) : "v"(w), "v"(h));
  return acc;
#endif
}

// one weight quad (4 packed pairs = 8 k) against 4 scalar (SGPR) h words
static __device__ __forceinline__ float dots4(u32x4 w, unsigned h0, unsigned h1,
                                              unsigned h2, unsigned h3, float a) {
  a = fdot2(w[0], h0, a);
  a = fdot2(w[1], h1, a);
  a = fdot2(w[2], h2, a);
  a = fdot2(w[3], h3, a);
  return a;
}

// ---------------- init ----------------
__global__ void k_init(int* slotmap, float* agg, float* cnt, float* hs0) {
  int i = blockIdx.x * blockDim.x + threadIdx.x;
  int stride = gridDim.x * blockDim.x;
  for (int idx = i; idx < 4096 * 128; idx += stride) agg[idx] = 0.f;
  for (int idx = i; idx < NNODES; idx += stride) slotmap[idx] = -1;
  for (int idx = i; idx < 4096; idx += stride) cnt[idx] = 0.f;
  for (int idx = i; idx < 8192; idx += stride) hs0[idx] = 0.f;
}

// ---------------- mark needed nodes ----------------
__global__ void k_mark(const int* __restrict__ input_ids, int* __restrict__ slotmap) {
  int p = blockIdx.x * blockDim.x + threadIdx.x;
  if (p < NPOS) atomicCAS(&slotmap[input_ids[p]], -1, p);
}

// ---------------- edge pass: masked segment-sum ----------------
__global__ void k_edge(const int* __restrict__ src, const int* __restrict__ dst,
                       const float* __restrict__ ev, const float* __restrict__ emb,
                       const int* __restrict__ slotmap,
                       float* __restrict__ agg, float* __restrict__ cnt) {
  int e = blockIdx.x * 256 + threadIdx.x;
  int lane = threadIdx.x & 63;
  int d = dst[e];
  int slot = slotmap[d];
  int sn = 0; float vv = 0.f;
  if (slot >= 0) { sn = src[e]; vv = ev[e]; }
  unsigned long long m = __ballot(slot >= 0);
  while (m) {
    int j = __ffsll(m) - 1;
    m &= m - 1;
    int sl = __shfl(slot, j);
    int s2 = __shfl(sn, j);
    float v = __shfl(vv, j);
    float2 em = *(const float2*)&emb[(size_t)s2 * 128 + 2 * lane];
    atomicAdd(&agg[sl * 128 + 2 * lane],     em.x * v);
    atomicAdd(&agg[sl * 128 + 2 * lane + 1], em.y * v);
    if (lane == 0) atomicAdd(&cnt[sl], 1.f);
  }
}

// ---------------- divide by count ----------------
__global__ void k_div(float* __restrict__ agg, const float* __restrict__ cnt) {
  int i = blockIdx.x * blockDim.x + threadIdx.x;
  agg[i] /= fmaxf(cnt[i >> 7], 1.f);
}

// ---------------- fuse W_f = w_ih @ W1, bias_f ----------------
__global__ void k_fuse(const float* __restrict__ w_ih, const float* __restrict__ W1,
                       const float* __restrict__ b1, const float* __restrict__ b_ih,
                       const float* __restrict__ b_hh,
                       float* __restrict__ Wf, float* __restrict__ bf) {
  int row = blockIdx.x;
  int e = threadIdx.x;
  float acc = 0.f;
  for (int m2 = 0; m2 < 256; ++m2) acc += w_ih[row * 256 + m2] * W1[m2 * 128 + e];
  Wf[row * 128 + e] = acc;
  if (e == 0) {
    float bacc = b_ih[row] + b_hh[row];
    for (int m2 = 0; m2 < 256; ++m2) bacc += w_ih[row * 256 + m2] * b1[m2];
    bf[row] = bacc;
  }
}

// ---------------- pre-gates GEMM: preg[t][s][m][q][32d] ----------------
__global__ __launch_bounds__(256, 2) void k_pregemm(
    const float* __restrict__ hnode, const float* __restrict__ Wf,
    const float* __restrict__ bf, const int* __restrict__ slotmap,
    const int* __restrict__ input_ids, float* __restrict__ preg) {
  __shared__ float Ash[64][132];
  __shared__ float Bsh[64][132];
  __shared__ int slots[64];
  int tid = threadIdx.x;
  int bm = (blockIdx.x & 63) * 64;
  int bn = (blockIdx.x >> 6) * 64;
  if (tid < 64) slots[tid] = slotmap[input_ids[bm + tid]];
  __syncthreads();
#pragma unroll
  for (int i = 0; i < 8; ++i) {
    int idx = tid + 256 * i;
    int r = idx >> 5, c = idx & 31;
    *(float4*)&Ash[r][c * 4] = *(const float4*)&hnode[slots[r] * 128 + c * 4];
    *(float4*)&Bsh[r][c * 4] = *(const float4*)&Wf[(bn + r) * 128 + c * 4];
  }
  __syncthreads();
  int tx = tid & 15, ty = tid >> 4;
  float acc[4][4] = {};
  for (int k = 0; k < 128; k += 4) {
    float4 a[4], bb[4];
#pragma unroll
    for (int i = 0; i < 4; ++i) a[i] = *(const float4*)&Ash[tx + 16 * i][k];
#pragma unroll
    for (int j = 0; j < 4; ++j) bb[j] = *(const float4*)&Bsh[ty + 16 * j][k];
#pragma unroll
    for (int i = 0; i < 4; ++i)
#pragma unroll
      for (int j = 0; j < 4; ++j)
        acc[i][j] += a[i].x * bb[j].x + a[i].y * bb[j].y + a[i].z * bb[j].z + a[i].w * bb[j].w;
  }
#pragma unroll
  for (int j = 0; j < 4; ++j) {
    int row = bn + ty + 16 * j;
    float bias = bf[row];
    int q  = row >> 8;
    int mm = (row >> 5) & 7;
    int dl = row & 31;
#pragma unroll
    for (int i = 0; i < 4; ++i) {
      int p = bm + tx + 16 * i;
      int s = p >> 7, tt = p & 127;
      preg[(((size_t)(tt * 32 + s) * 8 + mm) * 4 + q) * 32 + dl] = acc[i][j] + bias;
    }
  }
}

// ---------------- w_hh f32 -> packed fp16 three-way images (RNE) ----------------
// k_lstm mapping: tid = kseg*256 + dd owns gate rows q*256+dd (q=0..3),
// k-slice [64*kseg, 64*kseg+64) = 8 quads/gate. Quad (q, c=pair>>2):
//   q==0, c<6   -> REG    quad qr = c                (6 quads)
//   q==0, c>=6  -> LDS    lc = c-6                   (2)
//   q==1, c<7   -> LDS    lc = 2+c                   (7)   [9 LDS total]
//   q==1, c==7  -> STREAM sc = 14
//   q==2        -> STREAM sc = (c<7) ? 2c   : 15
//   q==3        -> STREAM sc = (c<7) ? 2c+1 : 16     [17 STREAM, consumption order]
__global__ void k_wcvt(const float* __restrict__ w_hh, unsigned* __restrict__ wR,
                       unsigned* __restrict__ wL, unsigned* __restrict__ wS) {
  int idx = blockIdx.x * 256 + threadIdx.x;   // 0..131071
  int row = idx >> 7;          // q*256 + dd
  int j   = idx & 127;         // pair index (k = 2j, 2j+1)
  float x0 = w_hh[(size_t)row * 256 + 2 * j];
  float x1 = w_hh[(size_t)row * 256 + 2 * j + 1];
  union { _Float16 f[2]; unsigned u; } pk;
  pk.f[0] = (_Float16)x0;
  pk.f[1] = (_Float16)x1;
  int q = row >> 8, dd = row & 255;
  int kseg = j >> 5, p = j & 31;
  int c = p >> 2, l = p & 3;
  int tid = kseg * 256 + dd;
  if (q == 0 && c < 6) {
    wR[(c * 4 + l) * 1024 + tid] = pk.u;
  } else if (q == 0) {
    wL[((c - 6) * 1024 + tid) * 4 + l] = pk.u;
  } else if (q == 1 && c < 7) {
    wL[((2 + c) * 1024 + tid) * 4 + l] = pk.u;
  } else if (q == 1) {
    wS[(14 * 1024 + tid) * 4 + l] = pk.u;
  } else if (q == 2) {
    wS[(((c < 7) ? (2 * c) : 15) * 1024 + tid) * 4 + l] = pk.u;
  } else {
    wS[(((c < 7) ? (2 * c + 1) : 16) * 1024 + tid) * 4 + l] = pk.u;
  }
}

// ---------------- LSTM: one sequence per CU; readlane h-broadcast ----------------
// R10/R13 both measured 1.6us/step with identical 17 ds_read_b128/thread/step;
// at ~12 cyc/b128 wave-inst the DS pipe (272 insts -> ~3300 cyc) is the binding
// constraint -- and HALF of it was 128 wave-uniform h-broadcast reads delivering
// 16 unique bytes each at full cost. Fix: ONE per-lane ds_read_b128 per wave
// (lane l reads h-quad l&31 => the wave holds the whole 512B h vector), then
// __builtin_amdgcn_readlane extracts this kseg's h words into SGPRs (VALU/SALU,
// off the DS pipe) feeding v_dot2_f32_f16's scalar operand slot. h DS-insts:
// 128 -> 16/step. New budget: DS ~2260 cyc, VMEM 2785 (bottleneck), VALU ~1800.
__global__ __launch_bounds__(1024) void k_lstm(
    const unsigned* __restrict__ wR, const unsigned* __restrict__ wL,
    const unsigned* __restrict__ wS, const float* __restrict__ preg,
    float* __restrict__ hs) {
  __shared__ __align__(16) unsigned whL[9 * 1024 * 4];   // 147456 B
  __shared__ __align__(16) unsigned h16[128];            // 512 B: 256 fp16 h
  __shared__ __align__(16) float    accb[3 * 256 * 4];   // 12288 B (16B stride)
  const int tid  = threadIdx.x;
  const int s    = blockIdx.x;
  const int kseg = tid >> 8;       // 0..3 : k-slice [64*kseg, 64*kseg+64)
  const int d    = tid & 255;
  const int lane = tid & 63;
  const bool owner = (kseg == 0);

  // ---- prologue: 6 quads -> VGPRs, 9 quads -> LDS (coalesced) ----
  u32x4 rq[6];
#pragma unroll
  for (int qr = 0; qr < 6; ++qr)
#pragma unroll
    for (int l = 0; l < 4; ++l)
      rq[qr][l] = wR[(qr * 4 + l) * 1024 + tid];
  {
    const u32x4* src = (const u32x4*)wL;
    u32x4* dst = (u32x4*)whL;
#pragma unroll
    for (int lc = 0; lc < 9; ++lc)
      dst[lc * 1024 + tid] = src[lc * 1024 + tid];
  }
  if (tid < 128) h16[tid] = 0u;    // h(0) = 0 (fp16 pairs)
  float c_st = 0.f;                // cell state (owners)
  __syncthreads();

  const u32x4* lq  = (const u32x4*)whL + tid;       // LDS quad lc at lq[lc*1024]
  const u32x4* sq  = (const u32x4*)wS + tid;        // stream quad sc at sq[sc*1024]

  for (int t = 0; t < TSTEPS; ++t) {
    // pre-gates (owners): issue early, consumed after the dots
    float pg[4] = {0.f, 0.f, 0.f, 0.f};
    if (owner) {
      const float* pb = preg + (((size_t)(t * 32 + s) * 8 + (d >> 5)) * 4) * 32
                        + (d & 31);
#pragma unroll
      for (int q = 0; q < 4; ++q) pg[q] = pb[q * 32];
    }
    // one ds_read_b128 per wave: lane l holds h-quad (l&31); the full 512B h
    // vector is in the wave's registers. readlane (wave-uniform src lane)
    // extracts this kseg's quads to SGPRs -- no further DS traffic.
    u32x4 hg = ((const u32x4*)h16)[lane & 31];
    // ---- dots: per c-chunk, 4 scalar h words vs 4 gate quads ----
    float a0 = 0.f, a1 = 0.f, a2 = 0.f, a3 = 0.f;
#pragma unroll
    for (int c = 0; c < 8; ++c) {
      int sl = (kseg << 3) + c;                        // wave-uniform source lane
      unsigned h0 = (unsigned)__builtin_amdgcn_readlane((int)hg[0], sl);
      unsigned h1 = (unsigned)__builtin_amdgcn_readlane((int)hg[1], sl);
      unsigned h2 = (unsigned)__builtin_amdgcn_readlane((int)hg[2], sl);
      unsigned h3 = (unsigned)__builtin_amdgcn_readlane((int)hg[3], sl);
      u32x4 w0 = (c < 6) ? rq[c] : lq[(c - 6) * 1024];
      u32x4 w1 = (c < 7) ? lq[(2 + c) * 1024] : sq[14 * 1024];
      u32x4 w2 = sq[((c < 7) ? (2 * c) : 15) * 1024];
      u32x4 w3 = sq[((c < 7) ? (2 * c + 1) : 16) * 1024];
      a0 = dots4(w0, h0, h1, h2, h3, a0);
      a1 = dots4(w1, h0, h1, h2, h3, a1);
      a2 = dots4(w2, h0, h1, h2, h3, a2);
      a3 = dots4(w3, h0, h1, h2, h3, a3);
    }
    // ---- publish partials (ksegs 1..3), 16B-stride conflict-free ----
    if (!owner) {
      f32x4 r; r.x = a0; r.y = a1; r.z = a2; r.w = a3;
      *(f32x4*)&accb[((kseg - 1) * 256 + d) * 4] = r;
    }
    __syncthreads();                 // partials visible; h16 reads done
    if (owner) {
      f32x4 r0 = *(const f32x4*)&accb[(0 * 256 + d) * 4];
      f32x4 r1 = *(const f32x4*)&accb[(1 * 256 + d) * 4];
      f32x4 r2 = *(const f32x4*)&accb[(2 * 256 + d) * 4];
      float gi = a0 + r0.x + r1.x + r2.x + pg[0];
      float gf = a1 + r0.y + r1.y + r2.y + pg[1];
      float gg = a2 + r0.z + r1.z + r2.z + pg[2];
      float go = a3 + r0.w + r1.w + r2.w + pg[3];
      float si = 1.f / (1.f + expf(-gi));
      float sf = 1.f / (1.f + expf(-gf));
      float so = 1.f / (1.f + expf(-go));
      float cc = sf * c_st + si * tanhf(gg);
      float hh = so * tanhf(cc);
      c_st = cc;
      ((_Float16*)h16)[d] = (_Float16)hh;                    // next-step h (fp16)
      hs[(size_t)(t + 1) * 8192 + s * 256 + d] = hh;         // f32 history
    }
    __syncthreads();                 // new h16 + accb reuse protected
  }
}

// ---------------- final: scores, softmax, BCE, argmax ----------------
__global__ void k_final(const float* __restrict__ hs, const int* __restrict__ mask,
                        const float* __restrict__ labels, const float* __restrict__ W2,
                        const float* __restrict__ b2, float* __restrict__ out) {
  __shared__ float scores[32];
  __shared__ float errpart[8];
  int tid = threadIdx.x;
  if (tid < 32) {
    int len = 0;
    for (int t = 0; t < 128; ++t) len += mask[tid * 128 + t];
    if (len < 1) len = 1;
    const float* hl = hs + (size_t)len * 8192 + tid * 256;
    float acc = b2[0];
    for (int k = 0; k < 256; ++k) acc += hl[k] * W2[k];
    scores[tid] = acc;
  }
  __syncthreads();
  if (tid < 8) {
    float sc[4];
#pragma unroll
    for (int i = 0; i < 4; ++i) sc[i] = scores[tid * 4 + i];
    float mx = fmaxf(fmaxf(sc[0], sc[1]), fmaxf(sc[2], sc[3]));
    float ex[4], ssum = 0.f;
#pragma unroll
    for (int i = 0; i < 4; ++i) { ex[i] = expf(sc[i] - mx); ssum += ex[i]; }
    float esum = 0.f; int am = 0; float best = -1e30f;
#pragma unroll
    for (int i = 0; i < 4; ++i) {
      float p = ex[i] / ssum;
      float li = labels[tid * 4 + i];
      esum += fmaxf(p, 0.f) - p * li + log1pf(expf(-fabsf(p)));
      if (p > best) { best = p; am = i; }
    }
    errpart[tid] = esum;
    out[1 + tid] = (float)am;
  }
  __syncthreads();
  if (tid == 0) {
    float e = 0.f;
    for (int i = 0; i < 8; ++i) e += errpart[i];
    out[0] = e / 32.f;
  }
}

extern "C" void kernel_launch(void* const* d_in, const int* in_sizes, int n_in,
                              void* d_out, int out_size, void* d_ws, size_t ws_size,
                              hipStream_t stream) {
  const int*   input_ids  = (const int*)d_in[0];
  const int*   input_mask = (const int*)d_in[1];
  const float* labels     = (const float*)d_in[2];
  const int*   src        = (const int*)d_in[3];
  const int*   dst        = (const int*)d_in[4];
  const float* ev         = (const float*)d_in[5];
  const float* node_emb   = (const float*)d_in[6];
  const float* W1         = (const float*)d_in[7];
  const float* b1         = (const float*)d_in[8];
  const float* w_ih       = (const float*)d_in[9];
  const float* w_hh       = (const float*)d_in[10];
  const float* b_ih       = (const float*)d_in[11];
  const float* b_hh       = (const float*)d_in[12];
  const float* W2         = (const float*)d_in[13];
  const float* b2         = (const float*)d_in[14];
  float* out = (float*)d_out;
  char* ws = (char*)d_ws;
  int*      slotmap = (int*)(ws + OFF_SLOT);
  float*    agg     = (float*)(ws + OFF_AGG);
  float*    cnt     = (float*)(ws + OFF_CNT);
  float*    Wf      = (float*)(ws + OFF_WF);
  float*    biasf   = (float*)(ws + OFF_BIASF);
  float*    preg    = (float*)(ws + OFF_PREG);
  float*    hs      = (float*)(ws + OFF_HS);
  unsigned* wRimg   = (unsigned*)(ws + OFF_WR);
  unsigned* wLimg   = (unsigned*)(ws + OFF_WL);
  unsigned* wSimg   = (unsigned*)(ws + OFF_WS);

  hipLaunchKernelGGL(k_init,    dim3(2048), dim3(256),  0, stream, slotmap, agg, cnt, hs);
  hipLaunchKernelGGL(k_mark,    dim3(16),   dim3(256),  0, stream, input_ids, slotmap);
  hipLaunchKernelGGL(k_edge,    dim3(6250), dim3(256),  0, stream, src, dst, ev, node_emb, slotmap, agg, cnt);
  hipLaunchKernelGGL(k_div,     dim3(2048), dim3(256),  0, stream, agg, cnt);
  hipLaunchKernelGGL(k_fuse,    dim3(1024), dim3(128),  0, stream, w_ih, W1, b1, b_ih, b_hh, Wf, biasf);
  hipLaunchKernelGGL(k_pregemm, dim3(1024), dim3(256),  0, stream, agg, Wf, biasf, slotmap, input_ids, preg);
  hipLaunchKernelGGL(k_wcvt,    dim3(512),  dim3(256),  0, stream, w_hh, wRimg, wLimg, wSimg);
  hipLaunchKernelGGL(k_lstm,    dim3(NSEQ), dim3(1024), 0, stream, wRimg, wLimg, wSimg, preg, hs);
  hipLaunchKernelGGL(k_final,   dim3(1),    dim3(64),   0, stream, hs, input_mask, labels, W2, b2, out);
}

// Round 15
// 374.480 us; speedup vs baseline: 1.0797x; 1.0797x over previous
//
#include <hip/hip_runtime.h>
#include <math.h>

#define NNODES 100000
#define NEDGES 1600000
#define NPOS   4096      // 32 seqs * 128 steps
#define NSEQ   32
#define TSTEPS 128

typedef float f32x4 __attribute__((ext_vector_type(4)));
typedef unsigned u32x4 __attribute__((ext_vector_type(4)));
typedef _Float16 h2v __attribute__((ext_vector_type(2)));

// ---- ws layout (bytes) ----
#define OFF_SLOT   0          // int[100000]  (dead after k_pregemm)
#define OFF_AGG    400128     // float[4096*128] (dead after k_pregemm; overlaid by wh16)
#define OFF_CNT    2497280    // float[4096]
#define OFF_WF     2513664    // float[1024*128]
#define OFF_BIASF  3037952    // float[1024]
#define OFF_PREG   3042048    // float[128][32s][8m][4q][32d]
#define OFF_HS     19819264   // float[129][32][256]
// fp16 weight images overlay the dead agg region (valid only after k_pregemm).
// Measured model (R10-R14): step time = DS wave-insts x ~12cyc (R10==R13: 290
// insts -> 3480 + epilogue = 3900 cyc) while VMEM (278KB @ ~100 B/cyc = 2785)
// has headroom; readlane redistribution loses to SGPR hazards (R14). So shift
// 2 LDS weight quads onto the VMEM stream: DS 242 insts (~2900), VMEM 311KB
// (~3110) -- balanced. h reads (8/thread) are at the 16B/lane floor.
//   wR: u32[24][1024]    6 quads/thread register-resident    98304 B
//   wL: u32x4[7][1024]   7 quads/thread LDS-resident        114688 B
//   wS: u32x4[19][1024]  19 quads/thread L2-streamed/step   311296 B
#define OFF_WR  OFF_AGG
#define OFF_WL  (OFF_AGG + 98304)
#define OFF_WS  (OFF_AGG + 213  * 1000 - 8)   // = OFF_AGG + 212992 (98304+114688)
#undef  OFF_WS
#define OFF_WS  (OFF_AGG + 212992)

// fp16 dot2 with f32 accumulate: D = w.h[0]*h.h[0] + w.h[1]*h.h[1] + acc.
static __device__ __forceinline__ float fdot2(unsigned w, unsigned h, float acc) {
#if __has_builtin(__builtin_amdgcn_fdot2)
  h2v wv, hv;
  __builtin_memcpy(&wv, &w, 4);
  __builtin_memcpy(&hv, &h, 4);
  return __builtin_amdgcn_fdot2(wv, hv, acc, false);
#else
  asm("v_dot2_f32_f16 %0, %1, %2, %0" : "+v"(acc) : "v"(w), "v"(h));
  return acc;
#endif
}

// one weight quad (4 packed pairs = 8 k) against one h quad
static __device__ __forceinline__ float dotq(u32x4 w, u32x4 h, float a) {
  a = fdot2(w[0], h[0], a);
  a = fdot2(w[1], h[1], a);
  a = fdot2(w[2], h[2], a);
  a = fdot2(w[3], h[3], a);
  return a;
}

// ---------------- init ----------------
__global__ void k_init(int* slotmap, float* agg, float* cnt, float* hs0) {
  int i = blockIdx.x * blockDim.x + threadIdx.x;
  int stride = gridDim.x * blockDim.x;
  for (int idx = i; idx < 4096 * 128; idx += stride) agg[idx] = 0.f;
  for (int idx = i; idx < NNODES; idx += stride) slotmap[idx] = -1;
  for (int idx = i; idx < 4096; idx += stride) cnt[idx] = 0.f;
  for (int idx = i; idx < 8192; idx += stride) hs0[idx] = 0.f;
}

// ---------------- mark needed nodes ----------------
__global__ void k_mark(const int* __restrict__ input_ids, int* __restrict__ slotmap) {
  int p = blockIdx.x * blockDim.x + threadIdx.x;
  if (p < NPOS) atomicCAS(&slotmap[input_ids[p]], -1, p);
}

// ---------------- edge pass: masked segment-sum ----------------
__global__ void k_edge(const int* __restrict__ src, const int* __restrict__ dst,
                       const float* __restrict__ ev, const float* __restrict__ emb,
                       const int* __restrict__ slotmap,
                       float* __restrict__ agg, float* __restrict__ cnt) {
  int e = blockIdx.x * 256 + threadIdx.x;
  int lane = threadIdx.x & 63;
  int d = dst[e];
  int slot = slotmap[d];
  int sn = 0; float vv = 0.f;
  if (slot >= 0) { sn = src[e]; vv = ev[e]; }
  unsigned long long m = __ballot(slot >= 0);
  while (m) {
    int j = __ffsll(m) - 1;
    m &= m - 1;
    int sl = __shfl(slot, j);
    int s2 = __shfl(sn, j);
    float v = __shfl(vv, j);
    float2 em = *(const float2*)&emb[(size_t)s2 * 128 + 2 * lane];
    atomicAdd(&agg[sl * 128 + 2 * lane],     em.x * v);
    atomicAdd(&agg[sl * 128 + 2 * lane + 1], em.y * v);
    if (lane == 0) atomicAdd(&cnt[sl], 1.f);
  }
}

// ---------------- divide by count ----------------
__global__ void k_div(float* __restrict__ agg, const float* __restrict__ cnt) {
  int i = blockIdx.x * blockDim.x + threadIdx.x;
  agg[i] /= fmaxf(cnt[i >> 7], 1.f);
}

// ---------------- fuse W_f = w_ih @ W1, bias_f ----------------
__global__ void k_fuse(const float* __restrict__ w_ih, const float* __restrict__ W1,
                       const float* __restrict__ b1, const float* __restrict__ b_ih,
                       const float* __restrict__ b_hh,
                       float* __restrict__ Wf, float* __restrict__ bf) {
  int row = blockIdx.x;
  int e = threadIdx.x;
  float acc = 0.f;
  for (int m2 = 0; m2 < 256; ++m2) acc += w_ih[row * 256 + m2] * W1[m2 * 128 + e];
  Wf[row * 128 + e] = acc;
  if (e == 0) {
    float bacc = b_ih[row] + b_hh[row];
    for (int m2 = 0; m2 < 256; ++m2) bacc += w_ih[row * 256 + m2] * b1[m2];
    bf[row] = bacc;
  }
}

// ---------------- pre-gates GEMM: preg[t][s][m][q][32d] ----------------
__global__ __launch_bounds__(256, 2) void k_pregemm(
    const float* __restrict__ hnode, const float* __restrict__ Wf,
    const float* __restrict__ bf, const int* __restrict__ slotmap,
    const int* __restrict__ input_ids, float* __restrict__ preg) {
  __shared__ float Ash[64][132];
  __shared__ float Bsh[64][132];
  __shared__ int slots[64];
  int tid = threadIdx.x;
  int bm = (blockIdx.x & 63) * 64;
  int bn = (blockIdx.x >> 6) * 64;
  if (tid < 64) slots[tid] = slotmap[input_ids[bm + tid]];
  __syncthreads();
#pragma unroll
  for (int i = 0; i < 8; ++i) {
    int idx = tid + 256 * i;
    int r = idx >> 5, c = idx & 31;
    *(float4*)&Ash[r][c * 4] = *(const float4*)&hnode[slots[r] * 128 + c * 4];
    *(float4*)&Bsh[r][c * 4] = *(const float4*)&Wf[(bn + r) * 128 + c * 4];
  }
  __syncthreads();
  int tx = tid & 15, ty = tid >> 4;
  float acc[4][4] = {};
  for (int k = 0; k < 128; k += 4) {
    float4 a[4], bb[4];
#pragma unroll
    for (int i = 0; i < 4; ++i) a[i] = *(const float4*)&Ash[tx + 16 * i][k];
#pragma unroll
    for (int j = 0; j < 4; ++j) bb[j] = *(const float4*)&Bsh[ty + 16 * j][k];
#pragma unroll
    for (int i = 0; i < 4; ++i)
#pragma unroll
      for (int j = 0; j < 4; ++j)
        acc[i][j] += a[i].x * bb[j].x + a[i].y * bb[j].y + a[i].z * bb[j].z + a[i].w * bb[j].w;
  }
#pragma unroll
  for (int j = 0; j < 4; ++j) {
    int row = bn + ty + 16 * j;
    float bias = bf[row];
    int q  = row >> 8;
    int mm = (row >> 5) & 7;
    int dl = row & 31;
#pragma unroll
    for (int i = 0; i < 4; ++i) {
      int p = bm + tx + 16 * i;
      int s = p >> 7, tt = p & 127;
      preg[(((size_t)(tt * 32 + s) * 8 + mm) * 4 + q) * 32 + dl] = acc[i][j] + bias;
    }
  }
}

// ---------------- w_hh f32 -> packed fp16 three-way images (RNE) ----------------
// k_lstm mapping: tid = kseg*256 + dd owns gate rows q*256+dd (q=0..3),
// k-slice [64*kseg, 64*kseg+64) = 8 quads/gate. Quad (q, c=pair>>2):
//   q==0, c<6   -> REG    quad qr = c                      (6 quads)
//   q==0, c>=6  -> LDS    lc = c-6                         (2)
//   q==1, c<5   -> LDS    lc = 2+c                         (5)  [7 LDS total]
//   q==1, c>=5  -> STREAM sc = 10+(c-5)*3                  (3)
//   q==2        -> STREAM sc = (c<5) ? 2c   : 11+(c-5)*3   (8)
//   q==3        -> STREAM sc = (c<5) ? 2c+1 : 12+(c-5)*3   (8)  [19, consumption order]
__global__ void k_wcvt(const float* __restrict__ w_hh, unsigned* __restrict__ wR,
                       unsigned* __restrict__ wL, unsigned* __restrict__ wS) {
  int idx = blockIdx.x * 256 + threadIdx.x;   // 0..131071
  int row = idx >> 7;          // q*256 + dd
  int j   = idx & 127;         // pair index (k = 2j, 2j+1)
  float x0 = w_hh[(size_t)row * 256 + 2 * j];
  float x1 = w_hh[(size_t)row * 256 + 2 * j + 1];
  union { _Float16 f[2]; unsigned u; } pk;
  pk.f[0] = (_Float16)x0;
  pk.f[1] = (_Float16)x1;
  int q = row >> 8, dd = row & 255;
  int kseg = j >> 5, p = j & 31;
  int c = p >> 2, l = p & 3;
  int tid = kseg * 256 + dd;
  if (q == 0 && c < 6) {
    wR[(c * 4 + l) * 1024 + tid] = pk.u;
  } else if (q == 0) {
    wL[((c - 6) * 1024 + tid) * 4 + l] = pk.u;
  } else if (q == 1 && c < 5) {
    wL[((2 + c) * 1024 + tid) * 4 + l] = pk.u;
  } else if (q == 1) {
    wS[((10 + (c - 5) * 3) * 1024 + tid) * 4 + l] = pk.u;
  } else if (q == 2) {
    wS[(((c < 5) ? (2 * c) : (11 + (c - 5) * 3)) * 1024 + tid) * 4 + l] = pk.u;
  } else {
    wS[(((c < 5) ? (2 * c + 1) : (12 + (c - 5) * 3)) * 1024 + tid) * 4 + l] = pk.u;
  }
}

// ---------------- LSTM: one sequence per CU; DS/VMEM-balanced weight split ----
// R10==R13 at 3900 cyc/step with identical ~290 DS wave-insts (x ~12 cyc =
// 3480 + epilogue) while VMEM (278KB, 2785 cyc) had headroom; R14's readlane
// redistribution lost to VALU->SGPR hazards. This round: shift 2 LDS weight
// quads to the L2 stream. DS reads 15/thread (~242 insts, ~2900 cyc); VMEM
// 311KB (~3110 cyc); 16 waves overlap VMEM at ~96% (R10/R13 measured).
__global__ __launch_bounds__(1024) void k_lstm(
    const unsigned* __restrict__ wR, const unsigned* __restrict__ wL,
    const unsigned* __restrict__ wS, const float* __restrict__ preg,
    float* __restrict__ hs) {
  __shared__ __align__(16) unsigned whL[7 * 1024 * 4];   // 114688 B
  __shared__ __align__(16) unsigned h16[128];            // 512 B: 256 fp16 h
  __shared__ __align__(16) float    accb[3 * 256 * 4];   // 12288 B (16B stride)
  const int tid  = threadIdx.x;
  const int s    = blockIdx.x;
  const int kseg = tid >> 8;       // 0..3 : k-slice [64*kseg, 64*kseg+64)
  const int d    = tid & 255;
  const bool owner = (kseg == 0);

  // ---- prologue: 6 quads -> VGPRs, 7 quads -> LDS (coalesced) ----
  u32x4 rq[6];
#pragma unroll
  for (int qr = 0; qr < 6; ++qr)
#pragma unroll
    for (int l = 0; l < 4; ++l)
      rq[qr][l] = wR[(qr * 4 + l) * 1024 + tid];
  {
    const u32x4* src = (const u32x4*)wL;
    u32x4* dst = (u32x4*)whL;
#pragma unroll
    for (int lc = 0; lc < 7; ++lc)
      dst[lc * 1024 + tid] = src[lc * 1024 + tid];
  }
  if (tid < 128) h16[tid] = 0u;    // h(0) = 0 (fp16 pairs)
  float c_st = 0.f;                // cell state (owners)
  __syncthreads();

  const u32x4* hqp = (const u32x4*)h16 + kseg * 8;  // 8 h-quads for this kseg
  const u32x4* lq  = (const u32x4*)whL + tid;       // LDS quad lc at lq[lc*1024]
  const u32x4* sq  = (const u32x4*)wS + tid;        // stream quad sc at sq[sc*1024]

  for (int t = 0; t < TSTEPS; ++t) {
    // pre-gates (owners): issue early, consumed after the dots
    float pg[4] = {0.f, 0.f, 0.f, 0.f};
    if (owner) {
      const float* pb = preg + (((size_t)(t * 32 + s) * 8 + (d >> 5)) * 4) * 32
                        + (d & 31);
#pragma unroll
      for (int q = 0; q < 4; ++q) pg[q] = pb[q * 32];
    }
    // ---- dots: per c-chunk, 1 h-quad vs 4 gate quads (reg/LDS/stream) ----
    float a0 = 0.f, a1 = 0.f, a2 = 0.f, a3 = 0.f;
#pragma unroll
    for (int c = 0; c < 8; ++c) {
      u32x4 h4 = hqp[c];                               // wave-uniform broadcast
      u32x4 w0 = (c < 6) ? rq[c] : lq[(c - 6) * 1024];
      u32x4 w1 = (c < 5) ? lq[(2 + c) * 1024] : sq[(10 + (c - 5) * 3) * 1024];
      u32x4 w2 = sq[((c < 5) ? (2 * c) : (11 + (c - 5) * 3)) * 1024];
      u32x4 w3 = sq[((c < 5) ? (2 * c + 1) : (12 + (c - 5) * 3)) * 1024];
      a0 = dotq(w0, h4, a0);
      a1 = dotq(w1, h4, a1);
      a2 = dotq(w2, h4, a2);
      a3 = dotq(w3, h4, a3);
    }
    // ---- publish partials (ksegs 1..3), 16B-stride conflict-free ----
    if (!owner) {
      f32x4 r; r.x = a0; r.y = a1; r.z = a2; r.w = a3;
      *(f32x4*)&accb[((kseg - 1) * 256 + d) * 4] = r;
    }
    __syncthreads();                 // partials visible; h16 reads done
    if (owner) {
      f32x4 r0 = *(const f32x4*)&accb[(0 * 256 + d) * 4];
      f32x4 r1 = *(const f32x4*)&accb[(1 * 256 + d) * 4];
      f32x4 r2 = *(const f32x4*)&accb[(2 * 256 + d) * 4];
      float gi = a0 + r0.x + r1.x + r2.x + pg[0];
      float gf = a1 + r0.y + r1.y + r2.y + pg[1];
      float gg = a2 + r0.z + r1.z + r2.z + pg[2];
      float go = a3 + r0.w + r1.w + r2.w + pg[3];
      float si = 1.f / (1.f + expf(-gi));
      float sf = 1.f / (1.f + expf(-gf));
      float so = 1.f / (1.f + expf(-go));
      float cc = sf * c_st + si * tanhf(gg);
      float hh = so * tanhf(cc);
      c_st = cc;
      ((_Float16*)h16)[d] = (_Float16)hh;                    // next-step h (fp16)
      hs[(size_t)(t + 1) * 8192 + s * 256 + d] = hh;         // f32 history
    }
    __syncthreads();                 // new h16 + accb reuse protected
  }
}

// ---------------- final: scores, softmax, BCE, argmax ----------------
__global__ void k_final(const float* __restrict__ hs, const int* __restrict__ mask,
                        const float* __restrict__ labels, const float* __restrict__ W2,
                        const float* __restrict__ b2, float* __restrict__ out) {
  __shared__ float scores[32];
  __shared__ float errpart[8];
  int tid = threadIdx.x;
  if (tid < 32) {
    int len = 0;
    for (int t = 0; t < 128; ++t) len += mask[tid * 128 + t];
    if (len < 1) len = 1;
    const float* hl = hs + (size_t)len * 8192 + tid * 256;
    float acc = b2[0];
    for (int k = 0; k < 256; ++k) acc += hl[k] * W2[k];
    scores[tid] = acc;
  }
  __syncthreads();
  if (tid < 8) {
    float sc[4];
#pragma unroll
    for (int i = 0; i < 4; ++i) sc[i] = scores[tid * 4 + i];
    float mx = fmaxf(fmaxf(sc[0], sc[1]), fmaxf(sc[2], sc[3]));
    float ex[4], ssum = 0.f;
#pragma unroll
    for (int i = 0; i < 4; ++i) { ex[i] = expf(sc[i] - mx); ssum += ex[i]; }
    float esum = 0.f; int am = 0; float best = -1e30f;
#pragma unroll
    for (int i = 0; i < 4; ++i) {
      float p = ex[i] / ssum;
      float li = labels[tid * 4 + i];
      esum += fmaxf(p, 0.f) - p * li + log1pf(expf(-fabsf(p)));
      if (p > best) { best = p; am = i; }
    }
    errpart[tid] = esum;
    out[1 + tid] = (float)am;
  }
  __syncthreads();
  if (tid == 0) {
    float e = 0.f;
    for (int i = 0; i < 8; ++i) e += errpart[i];
    out[0] = e / 32.f;
  }
}

extern "C" void kernel_launch(void* const* d_in, const int* in_sizes, int n_in,
                              void* d_out, int out_size, void* d_ws, size_t ws_size,
                              hipStream_t stream) {
  const int*   input_ids  = (const int*)d_in[0];
  const int*   input_mask = (const int*)d_in[1];
  const float* labels     = (const float*)d_in[2];
  const int*   src        = (const int*)d_in[3];
  const int*   dst        = (const int*)d_in[4];
  const float* ev         = (const float*)d_in[5];
  const float* node_emb   = (const float*)d_in[6];
  const float* W1         = (const float*)d_in[7];
  const float* b1         = (const float*)d_in[8];
  const float* w_ih       = (const float*)d_in[9];
  const float* w_hh       = (const float*)d_in[10];
  const float* b_ih       = (const float*)d_in[11];
  const float* b_hh       = (const float*)d_in[12];
  const float* W2         = (const float*)d_in[13];
  const float* b2         = (const float*)d_in[14];
  float* out = (float*)d_out;
  char* ws = (char*)d_ws;
  int*      slotmap = (int*)(ws + OFF_SLOT);
  float*    agg     = (float*)(ws + OFF_AGG);
  float*    cnt     = (float*)(ws + OFF_CNT);
  float*    Wf      = (float*)(ws + OFF_WF);
  float*    biasf   = (float*)(ws + OFF_BIASF);
  float*    preg    = (float*)(ws + OFF_PREG);
  float*    hs      = (float*)(ws + OFF_HS);
  unsigned* wRimg   = (unsigned*)(ws + OFF_WR);
  unsigned* wLimg   = (unsigned*)(ws + OFF_WL);
  unsigned* wSimg   = (unsigned*)(ws + OFF_WS);

  hipLaunchKernelGGL(k_init,    dim3(2048), dim3(256),  0, stream, slotmap, agg, cnt, hs);
  hipLaunchKernelGGL(k_mark,    dim3(16),   dim3(256),  0, stream, input_ids, slotmap);
  hipLaunchKernelGGL(k_edge,    dim3(6250), dim3(256),  0, stream, src, dst, ev, node_emb, slotmap, agg, cnt);
  hipLaunchKernelGGL(k_div,     dim3(2048), dim3(256),  0, stream, agg, cnt);
  hipLaunchKernelGGL(k_fuse,    dim3(1024), dim3(128),  0, stream, w_ih, W1, b1, b_ih, b_hh, Wf, biasf);
  hipLaunchKernelGGL(k_pregemm, dim3(1024), dim3(256),  0, stream, agg, Wf, biasf, slotmap, input_ids, preg);
  hipLaunchKernelGGL(k_wcvt,    dim3(512),  dim3(256),  0, stream, w_hh, wRimg, wLimg, wSimg);
  hipLaunchKernelGGL(k_lstm,    dim3(NSEQ), dim3(1024), 0, stream, wRimg, wLimg, wSimg, preg, hs);
  hipLaunchKernelGGL(k_final,   dim3(1),    dim3(64),   0, stream, hs, input_mask, labels, W2, b2, out);
}

// Round 16
// 333.663 us; speedup vs baseline: 1.2117x; 1.1223x over previous
//
#include <hip/hip_runtime.h>
#include <math.h>

#define NNODES 100000
#define NEDGES 1600000
#define NPOS   4096      // 32 seqs * 128 steps
#define NSEQ   32
#define TSTEPS 128

typedef float f32x4 __attribute__((ext_vector_type(4)));
typedef unsigned u32x4 __attribute__((ext_vector_type(4)));
typedef _Float16 h2v __attribute__((ext_vector_type(2)));

// ---- ws layout (bytes) ----
#define OFF_SLOT   0          // int[100000]  (dead after k_pregemm)
#define OFF_AGG    400128     // float[4096*128] (dead after k_pregemm; overlaid by wh16)
#define OFF_CNT    2497280    // float[4096]
#define OFF_WF     2513664    // float[1024*128]
#define OFF_BIASF  3037952    // float[1024]
#define OFF_PREG   3042048    // float[128][32s][8m][4q][32d]
#define OFF_HS     19819264   // float[129][32][256]
// fp16 weight images overlay the dead agg region (valid only after k_pregemm).
// Final measured model (R10-R15): at this decomposition the DS and VMEM pipes
// are CO-SATURATED at ~3900 cyc/step (R13 = R10; R15's DS->VMEM shift lost
// 730 cyc; R14's readlane lost to SGPR hazards; 512-thr variants lose TLP
// overlap). VALU floor 2100 cyc. R13 is the empirical optimum: 6 reg quads +
// 9 LDS quads + 17 streamed quads per thread at 1024 threads / 16 waves.
//   wR: u32[24][1024]    6 quads/thread register-resident    98304 B
//   wL: u32x4[9][1024]   9 quads/thread LDS-resident        147456 B
//   wS: u32x4[17][1024]  17 quads/thread L2-streamed/step   278528 B
#define OFF_WR  OFF_AGG
#define OFF_WL  (OFF_AGG + 98304)
#define OFF_WS  (OFF_AGG + 245760)

// fp16 dot2 with f32 accumulate: D = w.h[0]*h.h[0] + w.h[1]*h.h[1] + acc.
static __device__ __forceinline__ float fdot2(unsigned w, unsigned h, float acc) {
#if __has_builtin(__builtin_amdgcn_fdot2)
  h2v wv, hv;
  __builtin_memcpy(&wv, &w, 4);
  __builtin_memcpy(&hv, &h, 4);
  return __builtin_amdgcn_fdot2(wv, hv, acc, false);
#else
  asm("v_dot2_f32_f16 %0, %1, %2, %0" : "+v"(acc) : "v"(w), "v"(h));
  return acc;
#endif
}

// one weight quad (4 packed pairs = 8 k) against one h quad
static __device__ __forceinline__ float dotq(u32x4 w, u32x4 h, float a) {
  a = fdot2(w[0], h[0], a);
  a = fdot2(w[1], h[1], a);
  a = fdot2(w[2], h[2], a);
  a = fdot2(w[3], h[3], a);
  return a;
}

// ---------------- init ----------------
__global__ void k_init(int* slotmap, float* agg, float* cnt, float* hs0) {
  int i = blockIdx.x * blockDim.x + threadIdx.x;
  int stride = gridDim.x * blockDim.x;
  for (int idx = i; idx < 4096 * 128; idx += stride) agg[idx] = 0.f;
  for (int idx = i; idx < NNODES; idx += stride) slotmap[idx] = -1;
  for (int idx = i; idx < 4096; idx += stride) cnt[idx] = 0.f;
  for (int idx = i; idx < 8192; idx += stride) hs0[idx] = 0.f;
}

// ---------------- mark needed nodes ----------------
__global__ void k_mark(const int* __restrict__ input_ids, int* __restrict__ slotmap) {
  int p = blockIdx.x * blockDim.x + threadIdx.x;
  if (p < NPOS) atomicCAS(&slotmap[input_ids[p]], -1, p);
}

// ---------------- edge pass: masked segment-sum ----------------
__global__ void k_edge(const int* __restrict__ src, const int* __restrict__ dst,
                       const float* __restrict__ ev, const float* __restrict__ emb,
                       const int* __restrict__ slotmap,
                       float* __restrict__ agg, float* __restrict__ cnt) {
  int e = blockIdx.x * 256 + threadIdx.x;
  int lane = threadIdx.x & 63;
  int d = dst[e];
  int slot = slotmap[d];
  int sn = 0; float vv = 0.f;
  if (slot >= 0) { sn = src[e]; vv = ev[e]; }
  unsigned long long m = __ballot(slot >= 0);
  while (m) {
    int j = __ffsll(m) - 1;
    m &= m - 1;
    int sl = __shfl(slot, j);
    int s2 = __shfl(sn, j);
    float v = __shfl(vv, j);
    float2 em = *(const float2*)&emb[(size_t)s2 * 128 + 2 * lane];
    atomicAdd(&agg[sl * 128 + 2 * lane],     em.x * v);
    atomicAdd(&agg[sl * 128 + 2 * lane + 1], em.y * v);
    if (lane == 0) atomicAdd(&cnt[sl], 1.f);
  }
}

// ---------------- divide by count ----------------
__global__ void k_div(float* __restrict__ agg, const float* __restrict__ cnt) {
  int i = blockIdx.x * blockDim.x + threadIdx.x;
  agg[i] /= fmaxf(cnt[i >> 7], 1.f);
}

// ---------------- fuse W_f = w_ih @ W1, bias_f ----------------
__global__ void k_fuse(const float* __restrict__ w_ih, const float* __restrict__ W1,
                       const float* __restrict__ b1, const float* __restrict__ b_ih,
                       const float* __restrict__ b_hh,
                       float* __restrict__ Wf, float* __restrict__ bf) {
  int row = blockIdx.x;
  int e = threadIdx.x;
  float acc = 0.f;
  for (int m2 = 0; m2 < 256; ++m2) acc += w_ih[row * 256 + m2] * W1[m2 * 128 + e];
  Wf[row * 128 + e] = acc;
  if (e == 0) {
    float bacc = b_ih[row] + b_hh[row];
    for (int m2 = 0; m2 < 256; ++m2) bacc += w_ih[row * 256 + m2] * b1[m2];
    bf[row] = bacc;
  }
}

// ---------------- pre-gates GEMM: preg[t][s][m][q][32d] ----------------
__global__ __launch_bounds__(256, 2) void k_pregemm(
    const float* __restrict__ hnode, const float* __restrict__ Wf,
    const float* __restrict__ bf, const int* __restrict__ slotmap,
    const int* __restrict__ input_ids, float* __restrict__ preg) {
  __shared__ float Ash[64][132];
  __shared__ float Bsh[64][132];
  __shared__ int slots[64];
  int tid = threadIdx.x;
  int bm = (blockIdx.x & 63) * 64;
  int bn = (blockIdx.x >> 6) * 64;
  if (tid < 64) slots[tid] = slotmap[input_ids[bm + tid]];
  __syncthreads();
#pragma unroll
  for (int i = 0; i < 8; ++i) {
    int idx = tid + 256 * i;
    int r = idx >> 5, c = idx & 31;
    *(float4*)&Ash[r][c * 4] = *(const float4*)&hnode[slots[r] * 128 + c * 4];
    *(float4*)&Bsh[r][c * 4] = *(const float4*)&Wf[(bn + r) * 128 + c * 4];
  }
  __syncthreads();
  int tx = tid & 15, ty = tid >> 4;
  float acc[4][4] = {};
  for (int k = 0; k < 128; k += 4) {
    float4 a[4], bb[4];
#pragma unroll
    for (int i = 0; i < 4; ++i) a[i] = *(const float4*)&Ash[tx + 16 * i][k];
#pragma unroll
    for (int j = 0; j < 4; ++j) bb[j] = *(const float4*)&Bsh[ty + 16 * j][k];
#pragma unroll
    for (int i = 0; i < 4; ++i)
#pragma unroll
      for (int j = 0; j < 4; ++j)
        acc[i][j] += a[i].x * bb[j].x + a[i].y * bb[j].y + a[i].z * bb[j].z + a[i].w * bb[j].w;
  }
#pragma unroll
  for (int j = 0; j < 4; ++j) {
    int row = bn + ty + 16 * j;
    float bias = bf[row];
    int q  = row >> 8;
    int mm = (row >> 5) & 7;
    int dl = row & 31;
#pragma unroll
    for (int i = 0; i < 4; ++i) {
      int p = bm + tx + 16 * i;
      int s = p >> 7, tt = p & 127;
      preg[(((size_t)(tt * 32 + s) * 8 + mm) * 4 + q) * 32 + dl] = acc[i][j] + bias;
    }
  }
}

// ---------------- w_hh f32 -> packed fp16 three-way images (RNE) ----------------
// k_lstm mapping: tid = kseg*256 + dd owns gate rows q*256+dd (q=0..3),
// k-slice [64*kseg, 64*kseg+64) = 8 quads/gate. Quad (q, c=pair>>2):
//   q==0, c<6   -> REG    quad qr = c                (6 quads)
//   q==0, c>=6  -> LDS    lc = c-6                   (2)
//   q==1, c<7   -> LDS    lc = 2+c                   (7)   [9 LDS total]
//   q==1, c==7  -> STREAM sc = 14
//   q==2        -> STREAM sc = (c<7) ? 2c   : 15
//   q==3        -> STREAM sc = (c<7) ? 2c+1 : 16     [17 STREAM, consumption order]
__global__ void k_wcvt(const float* __restrict__ w_hh, unsigned* __restrict__ wR,
                       unsigned* __restrict__ wL, unsigned* __restrict__ wS) {
  int idx = blockIdx.x * 256 + threadIdx.x;   // 0..131071
  int row = idx >> 7;          // q*256 + dd
  int j   = idx & 127;         // pair index (k = 2j, 2j+1)
  float x0 = w_hh[(size_t)row * 256 + 2 * j];
  float x1 = w_hh[(size_t)row * 256 + 2 * j + 1];
  union { _Float16 f[2]; unsigned u; } pk;
  pk.f[0] = (_Float16)x0;
  pk.f[1] = (_Float16)x1;
  int q = row >> 8, dd = row & 255;
  int kseg = j >> 5, p = j & 31;
  int c = p >> 2, l = p & 3;
  int tid = kseg * 256 + dd;
  if (q == 0 && c < 6) {
    wR[(c * 4 + l) * 1024 + tid] = pk.u;
  } else if (q == 0) {
    wL[((c - 6) * 1024 + tid) * 4 + l] = pk.u;
  } else if (q == 1 && c < 7) {
    wL[((2 + c) * 1024 + tid) * 4 + l] = pk.u;
  } else if (q == 1) {
    wS[(14 * 1024 + tid) * 4 + l] = pk.u;
  } else if (q == 2) {
    wS[(((c < 7) ? (2 * c) : 15) * 1024 + tid) * 4 + l] = pk.u;
  } else {
    wS[(((c < 7) ? (2 * c + 1) : 16) * 1024 + tid) * 4 + l] = pk.u;
  }
}

// ---------------- LSTM: one sequence per CU; reg/LDS/L2-stream, 16 waves ----
// The R13 configuration -- empirical optimum of this family (334.3us total,
// k_lstm 205us = 3900 cyc/step). DS and VMEM pipes co-saturated: R15's shift
// of 2 quads DS->stream lost 730 cyc/step; R14's readlane h-distribution lost
// to VALU->SGPR hazards; 512-thread variants (R11/R12) lose the 16-wave TLP
// that overlaps VMEM at ~96% of floor. VALU floor 2100 cyc/step.
__global__ __launch_bounds__(1024) void k_lstm(
    const unsigned* __restrict__ wR, const unsigned* __restrict__ wL,
    const unsigned* __restrict__ wS, const float* __restrict__ preg,
    float* __restrict__ hs) {
  __shared__ __align__(16) unsigned whL[9 * 1024 * 4];   // 147456 B
  __shared__ __align__(16) unsigned h16[128];            // 512 B: 256 fp16 h
  __shared__ __align__(16) float    accb[3 * 256 * 4];   // 12288 B (16B stride)
  const int tid  = threadIdx.x;
  const int s    = blockIdx.x;
  const int kseg = tid >> 8;       // 0..3 : k-slice [64*kseg, 64*kseg+64)
  const int d    = tid & 255;
  const bool owner = (kseg == 0);

  // ---- prologue: 6 quads -> VGPRs, 9 quads -> LDS (coalesced) ----
  u32x4 rq[6];
#pragma unroll
  for (int qr = 0; qr < 6; ++qr)
#pragma unroll
    for (int l = 0; l < 4; ++l)
      rq[qr][l] = wR[(qr * 4 + l) * 1024 + tid];
  {
    const u32x4* src = (const u32x4*)wL;
    u32x4* dst = (u32x4*)whL;
#pragma unroll
    for (int lc = 0; lc < 9; ++lc)
      dst[lc * 1024 + tid] = src[lc * 1024 + tid];
  }
  if (tid < 128) h16[tid] = 0u;    // h(0) = 0 (fp16 pairs)
  float c_st = 0.f;                // cell state (owners)
  __syncthreads();

  const u32x4* hqp = (const u32x4*)h16 + kseg * 8;  // 8 h-quads for this kseg
  const u32x4* lq  = (const u32x4*)whL + tid;       // LDS quad lc at lq[lc*1024]
  const u32x4* sq  = (const u32x4*)wS + tid;        // stream quad sc at sq[sc*1024]

  for (int t = 0; t < TSTEPS; ++t) {
    // pre-gates (owners): issue early, consumed after the dots
    float pg[4] = {0.f, 0.f, 0.f, 0.f};
    if (owner) {
      const float* pb = preg + (((size_t)(t * 32 + s) * 8 + (d >> 5)) * 4) * 32
                        + (d & 31);
#pragma unroll
      for (int q = 0; q < 4; ++q) pg[q] = pb[q * 32];
    }
    // ---- dots: per c-chunk, 1 h-quad vs 4 gate quads (reg/LDS/stream) ----
    float a0 = 0.f, a1 = 0.f, a2 = 0.f, a3 = 0.f;
#pragma unroll
    for (int c = 0; c < 8; ++c) {
      u32x4 h4 = hqp[c];                               // wave-uniform broadcast
      u32x4 w0 = (c < 6) ? rq[c] : lq[(c - 6) * 1024];
      u32x4 w1 = (c < 7) ? lq[(2 + c) * 1024] : sq[14 * 1024];
      u32x4 w2 = sq[((c < 7) ? (2 * c) : 15) * 1024];
      u32x4 w3 = sq[((c < 7) ? (2 * c + 1) : 16) * 1024];
      a0 = dotq(w0, h4, a0);
      a1 = dotq(w1, h4, a1);
      a2 = dotq(w2, h4, a2);
      a3 = dotq(w3, h4, a3);
    }
    // ---- publish partials (ksegs 1..3), 16B-stride conflict-free ----
    if (!owner) {
      f32x4 r; r.x = a0; r.y = a1; r.z = a2; r.w = a3;
      *(f32x4*)&accb[((kseg - 1) * 256 + d) * 4] = r;
    }
    __syncthreads();                 // partials visible; h16 reads done
    if (owner) {
      f32x4 r0 = *(const f32x4*)&accb[(0 * 256 + d) * 4];
      f32x4 r1 = *(const f32x4*)&accb[(1 * 256 + d) * 4];
      f32x4 r2 = *(const f32x4*)&accb[(2 * 256 + d) * 4];
      float gi = a0 + r0.x + r1.x + r2.x + pg[0];
      float gf = a1 + r0.y + r1.y + r2.y + pg[1];
      float gg = a2 + r0.z + r1.z + r2.z + pg[2];
      float go = a3 + r0.w + r1.w + r2.w + pg[3];
      float si = 1.f / (1.f + expf(-gi));
      float sf = 1.f / (1.f + expf(-gf));
      float so = 1.f / (1.f + expf(-go));
      float cc = sf * c_st + si * tanhf(gg);
      float hh = so * tanhf(cc);
      c_st = cc;
      ((_Float16*)h16)[d] = (_Float16)hh;                    // next-step h (fp16)
      hs[(size_t)(t + 1) * 8192 + s * 256 + d] = hh;         // f32 history
    }
    __syncthreads();                 // new h16 + accb reuse protected
  }
}

// ---------------- final: scores, softmax, BCE, argmax ----------------
__global__ void k_final(const float* __restrict__ hs, const int* __restrict__ mask,
                        const float* __restrict__ labels, const float* __restrict__ W2,
                        const float* __restrict__ b2, float* __restrict__ out) {
  __shared__ float scores[32];
  __shared__ float errpart[8];
  int tid = threadIdx.x;
  if (tid < 32) {
    int len = 0;
    for (int t = 0; t < 128; ++t) len += mask[tid * 128 + t];
    if (len < 1) len = 1;
    const float* hl = hs + (size_t)len * 8192 + tid * 256;
    float acc = b2[0];
    for (int k = 0; k < 256; ++k) acc += hl[k] * W2[k];
    scores[tid] = acc;
  }
  __syncthreads();
  if (tid < 8) {
    float sc[4];
#pragma unroll
    for (int i = 0; i < 4; ++i) sc[i] = scores[tid * 4 + i];
    float mx = fmaxf(fmaxf(sc[0], sc[1]), fmaxf(sc[2], sc[3]));
    float ex[4], ssum = 0.f;
#pragma unroll
    for (int i = 0; i < 4; ++i) { ex[i] = expf(sc[i] - mx); ssum += ex[i]; }
    float esum = 0.f; int am = 0; float best = -1e30f;
#pragma unroll
    for (int i = 0; i < 4; ++i) {
      float p = ex[i] / ssum;
      float li = labels[tid * 4 + i];
      esum += fmaxf(p, 0.f) - p * li + log1pf(expf(-fabsf(p)));
      if (p > best) { best = p; am = i; }
    }
    errpart[tid] = esum;
    out[1 + tid] = (float)am;
  }
  __syncthreads();
  if (tid == 0) {
    float e = 0.f;
    for (int i = 0; i < 8; ++i) e += errpart[i];
    out[0] = e / 32.f;
  }
}

extern "C" void kernel_launch(void* const* d_in, const int* in_sizes, int n_in,
                              void* d_out, int out_size, void* d_ws, size_t ws_size,
                              hipStream_t stream) {
  const int*   input_ids  = (const int*)d_in[0];
  const int*   input_mask = (const int*)d_in[1];
  const float* labels     = (const float*)d_in[2];
  const int*   src        = (const int*)d_in[3];
  const int*   dst        = (const int*)d_in[4];
  const float* ev         = (const float*)d_in[5];
  const float* node_emb   = (const float*)d_in[6];
  const float* W1         = (const float*)d_in[7];
  const float* b1         = (const float*)d_in[8];
  const float* w_ih       = (const float*)d_in[9];
  const float* w_hh       = (const float*)d_in[10];
  const float* b_ih       = (const float*)d_in[11];
  const float* b_hh       = (const float*)d_in[12];
  const float* W2         = (const float*)d_in[13];
  const float* b2         = (const float*)d_in[14];
  float* out = (float*)d_out;
  char* ws = (char*)d_ws;
  int*      slotmap = (int*)(ws + OFF_SLOT);
  float*    agg     = (float*)(ws + OFF_AGG);
  float*    cnt     = (float*)(ws + OFF_CNT);
  float*    Wf      = (float*)(ws + OFF_WF);
  float*    biasf   = (float*)(ws + OFF_BIASF);
  float*    preg    = (float*)(ws + OFF_PREG);
  float*    hs      = (float*)(ws + OFF_HS);
  unsigned* wRimg   = (unsigned*)(ws + OFF_WR);
  unsigned* wLimg   = (unsigned*)(ws + OFF_WL);
  unsigned* wSimg   = (unsigned*)(ws + OFF_WS);

  hipLaunchKernelGGL(k_init,    dim3(2048), dim3(256),  0, stream, slotmap, agg, cnt, hs);
  hipLaunchKernelGGL(k_mark,    dim3(16),   dim3(256),  0, stream, input_ids, slotmap);
  hipLaunchKernelGGL(k_edge,    dim3(6250), dim3(256),  0, stream, src, dst, ev, node_emb, slotmap, agg, cnt);
  hipLaunchKernelGGL(k_div,     dim3(2048), dim3(256),  0, stream, agg, cnt);
  hipLaunchKernelGGL(k_fuse,    dim3(1024), dim3(128),  0, stream, w_ih, W1, b1, b_ih, b_hh, Wf, biasf);
  hipLaunchKernelGGL(k_pregemm, dim3(1024), dim3(256),  0, stream, agg, Wf, biasf, slotmap, input_ids, preg);
  hipLaunchKernelGGL(k_wcvt,    dim3(512),  dim3(256),  0, stream, w_hh, wRimg, wLimg, wSimg);
  hipLaunchKernelGGL(k_lstm,    dim3(NSEQ), dim3(1024), 0, stream, wRimg, wLimg, wSimg, preg, hs);
  hipLaunchKernelGGL(k_final,   dim3(1),    dim3(64),   0, stream, hs, input_mask, labels, W2, b2, out);
}

// Round 17
// 310.207 us; speedup vs baseline: 1.3034x; 1.0756x over previous
//
#include <hip/hip_runtime.h>
#include <math.h>

#define NNODES 100000
#define NEDGES 1600000
#define NPOS   4096      // 32 seqs * 128 steps
#define NSEQ   32
#define TSTEPS 128

typedef float f32x4 __attribute__((ext_vector_type(4)));
typedef unsigned u32x4 __attribute__((ext_vector_type(4)));
typedef _Float16 h2v __attribute__((ext_vector_type(2)));

// ---- ws layout (bytes) ----
#define OFF_SLOT   0          // int[100000]  (dead after k_pregemm)
#define OFF_AGG    400128     // float[4096*128] (dead after k_pregemm; overlaid by wh16)
#define OFF_CNT    2497280    // int[4096] edge counts per slot (doubles as cnt for k_div)
#define OFF_WF     2513664    // float[1024*128]; first 32KB used transiently as offs/curs
#define OFF_BIASF  3037952    // float[1024]
#define OFF_PREG   3042048    // float[128][32s][8m][4q][32d]; transiently int2 ebuf[2.09M]
#define OFF_HS     19819264   // float[129][32][256]
// fp16 weight images overlay the dead agg region (valid only after k_pregemm).
// Measured model (R10-R15): k_lstm's DS and VMEM pipes are co-saturated at
// ~3900 cyc/step; R13 split (6 reg + 9 LDS + 17 streamed quads, 1024thr) is
// the empirical optimum. R17: the OLD k_edge was atomic-throughput-bound
// (~8.4M fine-grained f32 atomicAdds, memory-side per R3/R5) -- replaced by
// bin-then-gather CSR (65K binning atomics, zero accumulation atomics).
//   wR: u32[24][1024]    6 quads/thread register-resident    98304 B
//   wL: u32x4[9][1024]   9 quads/thread LDS-resident        147456 B
//   wS: u32x4[17][1024]  17 quads/thread L2-streamed/step   278528 B
#define OFF_WR  OFF_AGG
#define OFF_WL  (OFF_AGG + 98304)
#define OFF_WS  (OFF_AGG + 245760)

// fp16 dot2 with f32 accumulate: D = w.h[0]*h.h[0] + w.h[1]*h.h[1] + acc.
static __device__ __forceinline__ float fdot2(unsigned w, unsigned h, float acc) {
#if __has_builtin(__builtin_amdgcn_fdot2)
  h2v wv, hv;
  __builtin_memcpy(&wv, &w, 4);
  __builtin_memcpy(&hv, &h, 4);
  return __builtin_amdgcn_fdot2(wv, hv, acc, false);
#else
  asm("v_dot2_f32_f16 %0, %1, %2, %0" : "+v"(acc) : "v"(w), "v"(h));
  return acc;
#endif
}

// one weight quad (4 packed pairs = 8 k) against one h quad
static __device__ __forceinline__ float dotq(u32x4 w, u32x4 h, float a) {
  a = fdot2(w[0], h[0], a);
  a = fdot2(w[1], h[1], a);
  a = fdot2(w[2], h[2], a);
  a = fdot2(w[3], h[3], a);
  return a;
}

// ---------------- init (agg zeroing dropped: k_acc fully writes it) ----------------
__global__ void k_init(int* slotmap, int* icnt, float* hs0) {
  int i = blockIdx.x * blockDim.x + threadIdx.x;
  int stride = gridDim.x * blockDim.x;
  for (int idx = i; idx < NNODES; idx += stride) slotmap[idx] = -1;
  for (int idx = i; idx < 4096; idx += stride) icnt[idx] = 0;
  for (int idx = i; idx < 8192; idx += stride) hs0[idx] = 0.f;
}

// ---------------- mark needed nodes ----------------
__global__ void k_mark(const int* __restrict__ input_ids, int* __restrict__ slotmap) {
  int p = blockIdx.x * blockDim.x + threadIdx.x;
  if (p < NPOS) atomicCAS(&slotmap[input_ids[p]], -1, p);
}

// ---------------- edge pass A: count marked edges per slot ----------------
__global__ void k_cnt(const int* __restrict__ dst, const int* __restrict__ slotmap,
                      int* __restrict__ icnt) {
  int e = blockIdx.x * 256 + threadIdx.x;
  int slot = slotmap[dst[e]];
  if (slot >= 0) atomicAdd(&icnt[slot], 1);
}

// ---------------- edge pass B: exclusive prefix over 4096 counts ----------------
// one block, 256 threads x 16 slots each; Hillis-Steele scan of thread totals.
__global__ void k_prefix(const int* __restrict__ icnt, int* __restrict__ offs,
                         int* __restrict__ curs) {
  __shared__ int part[256];
  int tid = threadIdx.x;
  int base = tid * 16;
  int local[16];
  int s = 0;
  for (int i = 0; i < 16; ++i) { local[i] = s; s += icnt[base + i]; }
  part[tid] = s;
  __syncthreads();
  for (int off = 1; off < 256; off <<= 1) {
    int v = part[tid];
    int add = (tid >= off) ? part[tid - off] : 0;
    __syncthreads();
    part[tid] = v + add;
    __syncthreads();
  }
  int excl = (tid == 0) ? 0 : part[tid - 1];
  for (int i = 0; i < 16; ++i) {
    int o = excl + local[i];
    offs[base + i] = o;
    curs[base + i] = o;
  }
}

// ---------------- edge pass C: scatter (src, ev) into per-slot bins ----------------
__global__ void k_scat(const int* __restrict__ dst, const int* __restrict__ slotmap,
                       const int* __restrict__ src, const float* __restrict__ ev,
                       int* __restrict__ curs, int2* __restrict__ ebuf) {
  int e = blockIdx.x * 256 + threadIdx.x;
  int slot = slotmap[dst[e]];
  if (slot >= 0) {
    int idx = atomicAdd(&curs[slot], 1);
    int2 r;
    r.x = src[e];
    r.y = __float_as_int(ev[e]);
    ebuf[idx] = r;
  }
}

// ---------------- edge pass D: per-slot gather-accumulate (no atomics) ----------------
// one wave per slot: lanes hold dims (2*lane, 2*lane+1); loop over the bin.
__global__ void k_acc(const int2* __restrict__ ebuf, const int* __restrict__ offs,
                      const int* __restrict__ icnt, const float* __restrict__ emb,
                      float* __restrict__ agg) {
  int wave = threadIdx.x >> 6;
  int lane = threadIdx.x & 63;
  int slot = blockIdx.x * 4 + wave;
  int base = offs[slot], n = icnt[slot];
  float a0 = 0.f, a1 = 0.f;
  for (int i = 0; i < n; ++i) {
    int2 r = ebuf[base + i];
    float2 em = *(const float2*)&emb[(size_t)r.x * 128 + 2 * lane];
    float v = __int_as_float(r.y);
    a0 += em.x * v;
    a1 += em.y * v;
  }
  float2 o;
  o.x = a0;
  o.y = a1;
  *(float2*)&agg[slot * 128 + 2 * lane] = o;
}

// ---------------- divide by count ----------------
__global__ void k_div(float* __restrict__ agg, const int* __restrict__ icnt) {
  int i = blockIdx.x * blockDim.x + threadIdx.x;
  agg[i] /= fmaxf((float)icnt[i >> 7], 1.f);
}

// ---------------- fuse W_f = w_ih @ W1, bias_f ----------------
__global__ void k_fuse(const float* __restrict__ w_ih, const float* __restrict__ W1,
                       const float* __restrict__ b1, const float* __restrict__ b_ih,
                       const float* __restrict__ b_hh,
                       float* __restrict__ Wf, float* __restrict__ bf) {
  int row = blockIdx.x;
  int e = threadIdx.x;
  float acc = 0.f;
  for (int m2 = 0; m2 < 256; ++m2) acc += w_ih[row * 256 + m2] * W1[m2 * 128 + e];
  Wf[row * 128 + e] = acc;
  if (e == 0) {
    float bacc = b_ih[row] + b_hh[row];
    for (int m2 = 0; m2 < 256; ++m2) bacc += w_ih[row * 256 + m2] * b1[m2];
    bf[row] = bacc;
  }
}

// ---------------- pre-gates GEMM: preg[t][s][m][q][32d] ----------------
__global__ __launch_bounds__(256, 2) void k_pregemm(
    const float* __restrict__ hnode, const float* __restrict__ Wf,
    const float* __restrict__ bf, const int* __restrict__ slotmap,
    const int* __restrict__ input_ids, float* __restrict__ preg) {
  __shared__ float Ash[64][132];
  __shared__ float Bsh[64][132];
  __shared__ int slots[64];
  int tid = threadIdx.x;
  int bm = (blockIdx.x & 63) * 64;
  int bn = (blockIdx.x >> 6) * 64;
  if (tid < 64) slots[tid] = slotmap[input_ids[bm + tid]];
  __syncthreads();
#pragma unroll
  for (int i = 0; i < 8; ++i) {
    int idx = tid + 256 * i;
    int r = idx >> 5, c = idx & 31;
    *(float4*)&Ash[r][c * 4] = *(const float4*)&hnode[slots[r] * 128 + c * 4];
    *(float4*)&Bsh[r][c * 4] = *(const float4*)&Wf[(bn + r) * 128 + c * 4];
  }
  __syncthreads();
  int tx = tid & 15, ty = tid >> 4;
  float acc[4][4] = {};
  for (int k = 0; k < 128; k += 4) {
    float4 a[4], bb[4];
#pragma unroll
    for (int i = 0; i < 4; ++i) a[i] = *(const float4*)&Ash[tx + 16 * i][k];
#pragma unroll
    for (int j = 0; j < 4; ++j) bb[j] = *(const float4*)&Bsh[ty + 16 * j][k];
#pragma unroll
    for (int i = 0; i < 4; ++i)
#pragma unroll
      for (int j = 0; j < 4; ++j)
        acc[i][j] += a[i].x * bb[j].x + a[i].y * bb[j].y + a[i].z * bb[j].z + a[i].w * bb[j].w;
  }
#pragma unroll
  for (int j = 0; j < 4; ++j) {
    int row = bn + ty + 16 * j;
    float bias = bf[row];
    int q  = row >> 8;
    int mm = (row >> 5) & 7;
    int dl = row & 31;
#pragma unroll
    for (int i = 0; i < 4; ++i) {
      int p = bm + tx + 16 * i;
      int s = p >> 7, tt = p & 127;
      preg[(((size_t)(tt * 32 + s) * 8 + mm) * 4 + q) * 32 + dl] = acc[i][j] + bias;
    }
  }
}

// ---------------- w_hh f32 -> packed fp16 three-way images (RNE) ----------------
// k_lstm mapping: tid = kseg*256 + dd owns gate rows q*256+dd (q=0..3),
// k-slice [64*kseg, 64*kseg+64) = 8 quads/gate. Quad (q, c=pair>>2):
//   q==0, c<6   -> REG    quad qr = c                (6 quads)
//   q==0, c>=6  -> LDS    lc = c-6                   (2)
//   q==1, c<7   -> LDS    lc = 2+c                   (7)   [9 LDS total]
//   q==1, c==7  -> STREAM sc = 14
//   q==2        -> STREAM sc = (c<7) ? 2c   : 15
//   q==3        -> STREAM sc = (c<7) ? 2c+1 : 16     [17 STREAM, consumption order]
__global__ void k_wcvt(const float* __restrict__ w_hh, unsigned* __restrict__ wR,
                       unsigned* __restrict__ wL, unsigned* __restrict__ wS) {
  int idx = blockIdx.x * 256 + threadIdx.x;   // 0..131071
  int row = idx >> 7;          // q*256 + dd
  int j   = idx & 127;         // pair index (k = 2j, 2j+1)
  float x0 = w_hh[(size_t)row * 256 + 2 * j];
  float x1 = w_hh[(size_t)row * 256 + 2 * j + 1];
  union { _Float16 f[2]; unsigned u; } pk;
  pk.f[0] = (_Float16)x0;
  pk.f[1] = (_Float16)x1;
  int q = row >> 8, dd = row & 255;
  int kseg = j >> 5, p = j & 31;
  int c = p >> 2, l = p & 3;
  int tid = kseg * 256 + dd;
  if (q == 0 && c < 6) {
    wR[(c * 4 + l) * 1024 + tid] = pk.u;
  } else if (q == 0) {
    wL[((c - 6) * 1024 + tid) * 4 + l] = pk.u;
  } else if (q == 1 && c < 7) {
    wL[((2 + c) * 1024 + tid) * 4 + l] = pk.u;
  } else if (q == 1) {
    wS[(14 * 1024 + tid) * 4 + l] = pk.u;
  } else if (q == 2) {
    wS[(((c < 7) ? (2 * c) : 15) * 1024 + tid) * 4 + l] = pk.u;
  } else {
    wS[(((c < 7) ? (2 * c + 1) : 16) * 1024 + tid) * 4 + l] = pk.u;
  }
}

// ---------------- LSTM: one sequence per CU; reg/LDS/L2-stream, 16 waves ----
// R13 configuration, unchanged -- empirical optimum (k_lstm 205us = 3900
// cyc/step, DS+VMEM co-saturated; VALU floor 2100 cyc).
__global__ __launch_bounds__(1024) void k_lstm(
    const unsigned* __restrict__ wR, const unsigned* __restrict__ wL,
    const unsigned* __restrict__ wS, const float* __restrict__ preg,
    float* __restrict__ hs) {
  __shared__ __align__(16) unsigned whL[9 * 1024 * 4];   // 147456 B
  __shared__ __align__(16) unsigned h16[128];            // 512 B: 256 fp16 h
  __shared__ __align__(16) float    accb[3 * 256 * 4];   // 12288 B (16B stride)
  const int tid  = threadIdx.x;
  const int s    = blockIdx.x;
  const int kseg = tid >> 8;       // 0..3 : k-slice [64*kseg, 64*kseg+64)
  const int d    = tid & 255;
  const bool owner = (kseg == 0);

  // ---- prologue: 6 quads -> VGPRs, 9 quads -> LDS (coalesced) ----
  u32x4 rq[6];
#pragma unroll
  for (int qr = 0; qr < 6; ++qr)
#pragma unroll
    for (int l = 0; l < 4; ++l)
      rq[qr][l] = wR[(qr * 4 + l) * 1024 + tid];
  {
    const u32x4* src = (const u32x4*)wL;
    u32x4* dst = (u32x4*)whL;
#pragma unroll
    for (int lc = 0; lc < 9; ++lc)
      dst[lc * 1024 + tid] = src[lc * 1024 + tid];
  }
  if (tid < 128) h16[tid] = 0u;    // h(0) = 0 (fp16 pairs)
  float c_st = 0.f;                // cell state (owners)
  __syncthreads();

  const u32x4* hqp = (const u32x4*)h16 + kseg * 8;  // 8 h-quads for this kseg
  const u32x4* lq  = (const u32x4*)whL + tid;       // LDS quad lc at lq[lc*1024]
  const u32x4* sq  = (const u32x4*)wS + tid;        // stream quad sc at sq[sc*1024]

  for (int t = 0; t < TSTEPS; ++t) {
    // pre-gates (owners): issue early, consumed after the dots
    float pg[4] = {0.f, 0.f, 0.f, 0.f};
    if (owner) {
      const float* pb = preg + (((size_t)(t * 32 + s) * 8 + (d >> 5)) * 4) * 32
                        + (d & 31);
#pragma unroll
      for (int q = 0; q < 4; ++q) pg[q] = pb[q * 32];
    }
    // ---- dots: per c-chunk, 1 h-quad vs 4 gate quads (reg/LDS/stream) ----
    float a0 = 0.f, a1 = 0.f, a2 = 0.f, a3 = 0.f;
#pragma unroll
    for (int c = 0; c < 8; ++c) {
      u32x4 h4 = hqp[c];                               // wave-uniform broadcast
      u32x4 w0 = (c < 6) ? rq[c] : lq[(c - 6) * 1024];
      u32x4 w1 = (c < 7) ? lq[(2 + c) * 1024] : sq[14 * 1024];
      u32x4 w2 = sq[((c < 7) ? (2 * c) : 15) * 1024];
      u32x4 w3 = sq[((c < 7) ? (2 * c + 1) : 16) * 1024];
      a0 = dotq(w0, h4, a0);
      a1 = dotq(w1, h4, a1);
      a2 = dotq(w2, h4, a2);
      a3 = dotq(w3, h4, a3);
    }
    // ---- publish partials (ksegs 1..3), 16B-stride conflict-free ----
    if (!owner) {
      f32x4 r; r.x = a0; r.y = a1; r.z = a2; r.w = a3;
      *(f32x4*)&accb[((kseg - 1) * 256 + d) * 4] = r;
    }
    __syncthreads();                 // partials visible; h16 reads done
    if (owner) {
      f32x4 r0 = *(const f32x4*)&accb[(0 * 256 + d) * 4];
      f32x4 r1 = *(const f32x4*)&accb[(1 * 256 + d) * 4];
      f32x4 r2 = *(const f32x4*)&accb[(2 * 256 + d) * 4];
      float gi = a0 + r0.x + r1.x + r2.x + pg[0];
      float gf = a1 + r0.y + r1.y + r2.y + pg[1];
      float gg = a2 + r0.z + r1.z + r2.z + pg[2];
      float go = a3 + r0.w + r1.w + r2.w + pg[3];
      float si = 1.f / (1.f + expf(-gi));
      float sf = 1.f / (1.f + expf(-gf));
      float so = 1.f / (1.f + expf(-go));
      float cc = sf * c_st + si * tanhf(gg);
      float hh = so * tanhf(cc);
      c_st = cc;
      ((_Float16*)h16)[d] = (_Float16)hh;                    // next-step h (fp16)
      hs[(size_t)(t + 1) * 8192 + s * 256 + d] = hh;         // f32 history
    }
    __syncthreads();                 // new h16 + accb reuse protected
  }
}

// ---------------- final: scores, softmax, BCE, argmax ----------------
__global__ void k_final(const float* __restrict__ hs, const int* __restrict__ mask,
                        const float* __restrict__ labels, const float* __restrict__ W2,
                        const float* __restrict__ b2, float* __restrict__ out) {
  __shared__ float scores[32];
  __shared__ float errpart[8];
  int tid = threadIdx.x;
  if (tid < 32) {
    int len = 0;
    for (int t = 0; t < 128; ++t) len += mask[tid * 128 + t];
    if (len < 1) len = 1;
    const float* hl = hs + (size_t)len * 8192 + tid * 256;
    float acc = b2[0];
    for (int k = 0; k < 256; ++k) acc += hl[k] * W2[k];
    scores[tid] = acc;
  }
  __syncthreads();
  if (tid < 8) {
    float sc[4];
#pragma unroll
    for (int i = 0; i < 4; ++i) sc[i] = scores[tid * 4 + i];
    float mx = fmaxf(fmaxf(sc[0], sc[1]), fmaxf(sc[2], sc[3]));
    float ex[4], ssum = 0.f;
#pragma unroll
    for (int i = 0; i < 4; ++i) { ex[i] = expf(sc[i] - mx); ssum += ex[i]; }
    float esum = 0.f; int am = 0; float best = -1e30f;
#pragma unroll
    for (int i = 0; i < 4; ++i) {
      float p = ex[i] / ssum;
      float li = labels[tid * 4 + i];
      esum += fmaxf(p, 0.f) - p * li + log1pf(expf(-fabsf(p)));
      if (p > best) { best = p; am = i; }
    }
    errpart[tid] = esum;
    out[1 + tid] = (float)am;
  }
  __syncthreads();
  if (tid == 0) {
    float e = 0.f;
    for (int i = 0; i < 8; ++i) e += errpart[i];
    out[0] = e / 32.f;
  }
}

extern "C" void kernel_launch(void* const* d_in, const int* in_sizes, int n_in,
                              void* d_out, int out_size, void* d_ws, size_t ws_size,
                              hipStream_t stream) {
  const int*   input_ids  = (const int*)d_in[0];
  const int*   input_mask = (const int*)d_in[1];
  const float* labels     = (const float*)d_in[2];
  const int*   src        = (const int*)d_in[3];
  const int*   dst        = (const int*)d_in[4];
  const float* ev         = (const float*)d_in[5];
  const float* node_emb   = (const float*)d_in[6];
  const float* W1         = (const float*)d_in[7];
  const float* b1         = (const float*)d_in[8];
  const float* w_ih       = (const float*)d_in[9];
  const float* w_hh       = (const float*)d_in[10];
  const float* b_ih       = (const float*)d_in[11];
  const float* b_hh       = (const float*)d_in[12];
  const float* W2         = (const float*)d_in[13];
  const float* b2         = (const float*)d_in[14];
  float* out = (float*)d_out;
  char* ws = (char*)d_ws;
  int*      slotmap = (int*)(ws + OFF_SLOT);
  float*    agg     = (float*)(ws + OFF_AGG);
  int*      icnt    = (int*)(ws + OFF_CNT);
  float*    Wf      = (float*)(ws + OFF_WF);
  int*      offs    = (int*)(ws + OFF_WF);            // transient (pre-k_fuse)
  int*      curs    = (int*)(ws + OFF_WF + 16384);    // transient (pre-k_fuse)
  float*    biasf   = (float*)(ws + OFF_BIASF);
  float*    preg    = (float*)(ws + OFF_PREG);
  int2*     ebuf    = (int2*)(ws + OFF_PREG);         // transient (pre-k_pregemm)
  float*    hs      = (float*)(ws + OFF_HS);
  unsigned* wRimg   = (unsigned*)(ws + OFF_WR);
  unsigned* wLimg   = (unsigned*)(ws + OFF_WL);
  unsigned* wSimg   = (unsigned*)(ws + OFF_WS);

  hipLaunchKernelGGL(k_init,    dim3(512),  dim3(256),  0, stream, slotmap, icnt, hs);
  hipLaunchKernelGGL(k_mark,    dim3(16),   dim3(256),  0, stream, input_ids, slotmap);
  hipLaunchKernelGGL(k_cnt,     dim3(6250), dim3(256),  0, stream, dst, slotmap, icnt);
  hipLaunchKernelGGL(k_prefix,  dim3(1),    dim3(256),  0, stream, icnt, offs, curs);
  hipLaunchKernelGGL(k_scat,    dim3(6250), dim3(256),  0, stream, dst, slotmap, src, ev, curs, ebuf);
  hipLaunchKernelGGL(k_acc,     dim3(1024), dim3(256),  0, stream, ebuf, offs, icnt, node_emb, agg);
  hipLaunchKernelGGL(k_div,     dim3(2048), dim3(256),  0, stream, agg, icnt);
  hipLaunchKernelGGL(k_fuse,    dim3(1024), dim3(128),  0, stream, w_ih, W1, b1, b_ih, b_hh, Wf, biasf);
  hipLaunchKernelGGL(k_pregemm, dim3(1024), dim3(256),  0, stream, agg, Wf, biasf, slotmap, input_ids, preg);
  hipLaunchKernelGGL(k_wcvt,    dim3(512),  dim3(256),  0, stream, w_hh, wRimg, wLimg, wSimg);
  hipLaunchKernelGGL(k_lstm,    dim3(NSEQ), dim3(1024), 0, stream, wRimg, wLimg, wSimg, preg, hs);
  hipLaunchKernelGGL(k_final,   dim3(1),    dim3(64),   0, stream, hs, input_mask, labels, W2, b2, out);
}